// Round 9
// baseline (224.215 us; speedup 1.0000x reference)
//
#include <hip/hip_runtime.h>
#include <stdint.h>

#define F0    2048      // base input features (= GEMM K)
#define EROWS 512       // embed rows per level
#define NOUT  2048      // output features (= GEMM N)
#define MROWS 8192      // batch (= GEMM M)

typedef __attribute__((ext_vector_type(8))) short bf16x8;
typedef __attribute__((ext_vector_type(4))) float f32x4;
typedef __attribute__((ext_vector_type(8))) unsigned short u16x8;

typedef const __attribute__((address_space(1))) unsigned char ga_t;
typedef __attribute__((address_space(3))) unsigned char lds_t;

__device__ __forceinline__ void async_load16(const void* g, void* l) {
  __builtin_amdgcn_global_load_lds((ga_t*)g, (lds_t*)l, 16, 0, 0);
}

__device__ __forceinline__ unsigned short f2bf(float f) {
  unsigned int u = __builtin_bit_cast(unsigned int, f);
  u += 0x7fffu + ((u >> 16) & 1u);   // round-to-nearest-even
  return (unsigned short)(u >> 16);
}

// ---------------------------------------------------------------------------
// Expand one dense output row per block DIRECTLY FROM COO (no CSR build).
// Block r scans rows[] with coalesced int4 loads (L2-resident). Direct
// (c<F0) -> LDS scatter-add; indirect (c>=F0) -> list, then register AXPY
// against prior dense rows Dsrc[c-F0].
// Blocks [nrows, nrows+ncast): x -> bf16 cast chunk. Round-9 change: the
// cast (independent of ALL expand levels) is no longer sliced across the
// serial chain — launch 1 carries all 2048 cast blocks; launches 2-4 carry
// none. This removes 3 serialized ~5-6 us cast slices from the dependent
// chain and runs the 96 MB cast at full bandwidth once.
// ---------------------------------------------------------------------------
template <bool BF16OUT>
__global__ __launch_bounds__(256) void expand_scan_kernel(
    const int* __restrict__ rows, const int* __restrict__ cols,
    const float* __restrict__ vals, int nnz,
    const float* __restrict__ Dsrc, void* __restrict__ out, int nrows,
    const float* __restrict__ x, unsigned short* __restrict__ Ab, int cast_base)
{
  const int b = blockIdx.x;
  const int tid = threadIdx.x;

  if (b >= nrows) {
    // ---- x cast: each block handles 1024 vec8 (8192 floats in, bf16 out)
    const int cb = cast_base + (b - nrows);
    const float4* xp = (const float4*)x;
    u16x8* ap = (u16x8*)Ab;
#pragma unroll
    for (int it = 0; it < 4; ++it) {
      int i = cb * 1024 + it * 256 + tid;
      float4 a = xp[2 * i], c = xp[2 * i + 1];
      u16x8 o;
      o[0] = f2bf(a.x); o[1] = f2bf(a.y); o[2] = f2bf(a.z); o[3] = f2bf(a.w);
      o[4] = f2bf(c.x); o[5] = f2bf(c.y); o[6] = f2bf(c.z); o[7] = f2bf(c.w);
      ap[i] = o;
    }
    return;
  }

  const int r = b;
  __shared__ float acc[F0];
  __shared__ int   icol[128];
  __shared__ float ival[128];
  __shared__ int   icnt;

  float4* a4 = (float4*)acc;
  a4[tid * 2]     = (float4){0.f, 0.f, 0.f, 0.f};
  a4[tid * 2 + 1] = (float4){0.f, 0.f, 0.f, 0.f};
  if (tid == 0) icnt = 0;
  __syncthreads();

  // --- COO scan: coalesced int4 over rows[]; col/val loaded only on match
#define HANDLE(kk) do {                                                       \
    int c_ = cols[kk]; float v_ = vals[kk];                                   \
    if (c_ < F0) atomicAdd(&acc[c_], v_);                                     \
    else { int p_ = atomicAdd(&icnt, 1);                                      \
           if (p_ < 128) { icol[p_] = c_ - F0; ival[p_] = v_; } }             \
  } while (0)

  const int n4 = nnz >> 2;
  for (int gq = tid; gq < n4; gq += 256) {
    const int k = gq * 4;
    int4 rr = *(const int4*)(rows + k);
    if (rr.x == r) HANDLE(k);
    if (rr.y == r) HANDLE(k + 1);
    if (rr.z == r) HANDLE(k + 2);
    if (rr.w == r) HANDLE(k + 3);
  }
  for (int k = (n4 << 2) + tid; k < nnz; k += 256)
    if (rows[k] == r) HANDLE(k);
#undef HANDLE
  __syncthreads();
  int n = icnt; if (n > 128) n = 128;

  float4 q0 = a4[tid * 2], q1 = a4[tid * 2 + 1];
  for (int j = 0; j < n; ++j) {
    const float4* src = (const float4*)(Dsrc + (size_t)icol[j] * F0) + tid * 2;
    float v = ival[j];
    float4 s0 = src[0], s1 = src[1];
    q0.x += v * s0.x; q0.y += v * s0.y; q0.z += v * s0.z; q0.w += v * s0.w;
    q1.x += v * s1.x; q1.y += v * s1.y; q1.z += v * s1.z; q1.w += v * s1.w;
  }

  if (BF16OUT) {
    u16x8 o;
    o[0] = f2bf(q0.x); o[1] = f2bf(q0.y); o[2] = f2bf(q0.z); o[3] = f2bf(q0.w);
    o[4] = f2bf(q1.x); o[5] = f2bf(q1.y); o[6] = f2bf(q1.z); o[7] = f2bf(q1.w);
    ((u16x8*)out)[(size_t)r * 256 + tid] = o;
  } else {
    float4* dst = (float4*)out + (size_t)r * 512 + tid * 2;
    dst[0] = q0; dst[1] = q1;
  }
}

// ---------------------------------------------------------------------------
// GEMM v6 [round-7/8 verbatim — measured 58 us / MfmaUtil 46%]:
// 256x256 tile, BK=64, 8 waves (2Mx4N), XCD swizzle, quadrant-matched
// staging regions (sA=[qm][wr][64][64], sB=[qn][wc][32][64]) -> wave-
// independent region usage -> 2-barrier/tile schedule, uniform read
// clusters (4,8,8,4), every read {vm;BAR}-anchored. See round-7 ledger.
// ---------------------------------------------------------------------------
__global__ __launch_bounds__(512, 2) void gemm256_kernel(
    const unsigned short* __restrict__ A, const unsigned short* __restrict__ B,
    float* __restrict__ C)
{
  constexpr int K  = F0;        // 2048
  constexpr int N  = NOUT;      // 2048
  constexpr int NT = K / 64;    // 32 K-tiles

  extern __shared__ __align__(16) unsigned short lds[];
  unsigned short* sA = lds;           // [2 buf][qm:2][wr:2][64][64] bf16 = 64 KiB
  unsigned short* sB = lds + 32768;   // [2 buf][qn:2][wc:4][32][64] bf16 = 64 KiB

  const int tid  = threadIdx.x;
  const int lane = tid & 63;
  const int w    = tid >> 6;          // 0..7
  const int wr   = w >> 2;            // 0..1
  const int wc   = w & 3;             // 0..3
  const int mm   = lane & 15;
  const int g    = lane >> 4;         // 0..3
  const int sx   = mm & 7;

  // XCD-chunked bijective swizzle
  const int flat = blockIdx.y * 8 + blockIdx.x;   // gridDim = (8, 32)
  const int nid  = (flat & 7) * 32 + (flat >> 3);
  const int bm   = nid >> 3;          // 0..31
  const int bn   = nid & 7;           // 0..7

  const unsigned short* Ag = A + (size_t)bm * 256 * K;
  const unsigned short* Bg = B + (size_t)bn * 256 * K;

  const int    r0    = tid >> 3;
  const int    c0    = (tid & 7) ^ (r0 & 7);
  const size_t gA0   = (size_t)((r0 & 63) + (r0 >> 6) * 128) * K + c0 * 8;
  const size_t gB0   = (size_t)((r0 & 31) + (r0 >> 5) * 64)  * K + c0 * 8;
  const int    loff0 = tid * 8;
  const int    loff1 = 4096 + tid * 8;

#define STG_A(buf, qm, t) do {                                                \
    async_load16(Ag + gA0 + (size_t)(qm) * 64 * K + (size_t)(t) * 64,         \
                 sA + (buf) * 16384 + (qm) * 8192 + loff0);                   \
    async_load16(Ag + gA0 + (size_t)(qm) * 64 * K + (size_t)128 * K +         \
                 (size_t)(t) * 64,                                            \
                 sA + (buf) * 16384 + (qm) * 8192 + loff1);                   \
  } while (0)

#define STG_B(buf, qn, t) do {                                                \
    async_load16(Bg + gB0 + (size_t)(qn) * 32 * K + (size_t)(t) * 64,         \
                 sB + (buf) * 16384 + (qn) * 8192 + loff0);                   \
    async_load16(Bg + gB0 + (size_t)(qn) * 32 * K + (size_t)128 * K +         \
                 (size_t)(t) * 64,                                            \
                 sB + (buf) * 16384 + (qn) * 8192 + loff1);                   \
  } while (0)

  const unsigned short* paB = sA + (wr * 64 + mm) * 64;
  const unsigned short* pbB = sB + (wc * 32 + mm) * 64;
  const int s0 = ((0 * 4 + g) ^ sx) * 8;
  const int s1 = ((1 * 4 + g) ^ sx) * 8;

  bf16x8 afP[4][2];
  bf16x8 afQ[4][2];
  bf16x8 bf0A[2][2], bf0B[2][2];
  bf16x8 bf1[2][2];

#define LDA(dst, buf, qm) do {                                                \
    const unsigned short* p_ = paB + (buf) * 16384 + (qm) * 8192;             \
    _Pragma("unroll") for (int tm = 0; tm < 4; ++tm) {                        \
      dst[tm][0] = *(const bf16x8*)(p_ + tm * 1024 + s0);                     \
      dst[tm][1] = *(const bf16x8*)(p_ + tm * 1024 + s1);                     \
    } } while (0)

#define LDB(dst, buf, qn) do {                                                \
    const unsigned short* p_ = pbB + (buf) * 16384 + (qn) * 8192;             \
    _Pragma("unroll") for (int tn = 0; tn < 2; ++tn) {                        \
      dst[tn][0] = *(const bf16x8*)(p_ + tn * 1024 + s0);                     \
      dst[tn][1] = *(const bf16x8*)(p_ + tn * 1024 + s1);                     \
    } } while (0)

#define MFMA_Q(qm, qn, afX, bfX) do {                                         \
    __builtin_amdgcn_s_setprio(1);                                            \
    _Pragma("unroll") for (int tm = 0; tm < 4; ++tm)                          \
    _Pragma("unroll") for (int tn = 0; tn < 2; ++tn) {                        \
      acc[(qm)*4+tm][(qn)*2+tn] = __builtin_amdgcn_mfma_f32_16x16x32_bf16(    \
          afX[tm][0], bfX[tn][0], acc[(qm)*4+tm][(qn)*2+tn], 0, 0, 0);        \
      acc[(qm)*4+tm][(qn)*2+tn] = __builtin_amdgcn_mfma_f32_16x16x32_bf16(    \
          afX[tm][1], bfX[tn][1], acc[(qm)*4+tm][(qn)*2+tn], 0, 0, 0);        \
    }                                                                         \
    __builtin_amdgcn_s_setprio(0);                                            \
  } while (0)

#define CFENCE     asm volatile("" ::: "memory")
#define BAR        do { CFENCE; __builtin_amdgcn_s_barrier(); CFENCE; } while (0)
#define SCHED0     __builtin_amdgcn_sched_barrier(0)
#define WAIT_VM(n) asm volatile("s_waitcnt vmcnt(" #n ")" ::: "memory")

  f32x4 acc[8][4];
#pragma unroll
  for (int i = 0; i < 8; ++i)
#pragma unroll
    for (int j = 0; j < 4; ++j) acc[i][j] = (f32x4)0.f;

  // --- prologue
  STG_B(0, 0, 0); STG_B(0, 1, 0);
  STG_A(0, 0, 0); STG_A(0, 1, 0);
  STG_B(1, 0, 1); STG_B(1, 1, 1);
  STG_A(1, 0, 1);
  WAIT_VM(6);
  BAR; SCHED0;
  LDA(afP, 0, 0);
  LDB(bf0A, 0, 0);

#define TILE(buf, nbuf, BF0C, BF0N, t) do {                                   \
    /* P1 */                                                                  \
    STG_A(nbuf, 1, (t) + 1);                                                  \
    LDB(bf1, buf, 1);                                                         \
    MFMA_Q(0, 0, afP, BF0C);                                                  \
    /* P2 */                                                                  \
    WAIT_VM(8);                                                               \
    BAR; SCHED0;                                                              \
    LDA(afQ, buf, 1);                                                         \
    MFMA_Q(0, 1, afP, bf1);                                                   \
    /* P3 */                                                                  \
    STG_B(buf, 0, (t) + 2);                                                   \
    WAIT_VM(2);                                                               \
    BAR; SCHED0;                                                              \
    LDA(afP, nbuf, 0);                                                        \
    MFMA_Q(1, 1, afQ, bf1);                                                   \
    /* P4 */                                                                  \
    STG_B(buf, 1, (t) + 2);                                                   \
    STG_A(buf, 0, (t) + 2);                                                   \
    LDB(BF0N, nbuf, 0);                                                       \
    MFMA_Q(1, 0, afQ, BF0C);                                                  \
  } while (0)

  for (int tp = 0; tp < 15; ++tp) {            // t = 0..29
    const int t0 = 2 * tp;
    TILE(0, 1, bf0A, bf0B, t0);
    TILE(1, 0, bf0B, bf0A, t0 + 1);
  }

  // --- t = 30
  {
    STG_A(1, 1, 31);
    LDB(bf1, 0, 1);
    MFMA_Q(0, 0, afP, bf0A);
    WAIT_VM(8); BAR; SCHED0;
    LDA(afQ, 0, 1);
    MFMA_Q(0, 1, afP, bf1);
    WAIT_VM(2); BAR; SCHED0;
    LDA(afP, 1, 0);
    MFMA_Q(1, 1, afQ, bf1);
    LDB(bf0B, 1, 0);
    MFMA_Q(1, 0, afQ, bf0A);
  }
  // --- t = 31
  {
    LDB(bf1, 1, 1);
    MFMA_Q(0, 0, afP, bf0B);
    WAIT_VM(0); BAR; SCHED0;
    LDA(afQ, 1, 1);
    MFMA_Q(0, 1, afP, bf1);
    MFMA_Q(1, 1, afQ, bf1);
    MFMA_Q(1, 0, afQ, bf0B);
  }

  // --- epilogue
  const int rowb = bm * 256 + wr * 128 + g * 4;
  const int colb = bn * 256 + wc * 64 + mm;
#pragma unroll
  for (int im = 0; im < 8; ++im) {
#pragma unroll
    for (int in2 = 0; in2 < 4; ++in2) {
      const int row = rowb + im * 16;
      const int col = colb + in2 * 16;
#pragma unroll
      for (int r = 0; r < 4; ++r)
        C[(size_t)(row + r) * N + col] = acc[im][in2][r];
    }
  }

#undef STG_A
#undef STG_B
#undef LDA
#undef LDB
#undef MFMA_Q
#undef TILE
#undef CFENCE
#undef BAR
#undef SCHED0
#undef WAIT_VM
}

// ---------------------------------------------------------------------------
extern "C" void kernel_launch(void* const* d_in, const int* in_sizes, int n_in,
                              void* d_out, int out_size, void* d_ws, size_t ws_size,
                              hipStream_t stream)
{
  const float* x   = (const float*)d_in[0];
  const int*   er0 = (const int*)d_in[1];
  const int*   ec0 = (const int*)d_in[2];
  const float* ev0 = (const float*)d_in[3];
  const int*   er1 = (const int*)d_in[4];
  const int*   ec1 = (const int*)d_in[5];
  const float* ev1 = (const float*)d_in[6];
  const int*   er2 = (const int*)d_in[7];
  const int*   ec2 = (const int*)d_in[8];
  const float* ev2 = (const float*)d_in[9];
  const int*   mr  = (const int*)d_in[10];
  const int*   mc  = (const int*)d_in[11];
  const float* mv  = (const float*)d_in[12];
  const int nnz_e0 = in_sizes[1];
  const int nnz_e1 = in_sizes[4];
  const int nnz_e2 = in_sizes[7];
  const int nnz_m  = in_sizes[10];

  // workspace layout (CSR regions retired but offsets kept stable)
  int*   rp_all = (int*)d_ws;                              // (unused)
  int*   cc_all = rp_all + 4 * 4096;                       // (unused)
  float* cv_all = (float*)(cc_all + 48 * 1024);            // (unused)
  float* D      = (float*)(cv_all + 48 * 1024);            // [3*EROWS][F0] fp32 (12 MB)
  unsigned short* Mb = (unsigned short*)(D + (size_t)3 * EROWS * F0);  // 8 MB
  unsigned short* Ab = Mb + (size_t)NOUT * F0;             // 32 MB

  // 1) level-0 expand + ALL 2048 x-cast blocks (cast depends only on x;
  //    running it once here removes 3 serialized slices from the chain)
  hipLaunchKernelGGL((expand_scan_kernel<false>), dim3(EROWS + 2048), dim3(256), 0, stream,
                     er0, ec0, ev0, nnz_e0,
                     D, (void*)D, EROWS, x, Ab, 0);
  // 2-3) pure expand launches (512 blocks each, latency-bound)
  hipLaunchKernelGGL((expand_scan_kernel<false>), dim3(EROWS), dim3(256), 0, stream,
                     er1, ec1, ev1, nnz_e1,
                     D, (void*)(D + (size_t)EROWS * F0), EROWS, x, Ab, 0);
  hipLaunchKernelGGL((expand_scan_kernel<false>), dim3(EROWS), dim3(256), 0, stream,
                     er2, ec2, ev2, nnz_e2,
                     D, (void*)(D + (size_t)2 * EROWS * F0), EROWS, x, Ab, 0);
  // 4) main expand (2048 blocks)
  hipLaunchKernelGGL((expand_scan_kernel<true>), dim3(NOUT), dim3(256), 0, stream,
                     mr, mc, mv, nnz_m,
                     D, (void*)Mb, NOUT, x, Ab, 0);

  // 5) out = x @ M^T  (round-7 GEMM, unchanged)
  hipFuncSetAttribute(reinterpret_cast<const void*>(gemm256_kernel),
                      hipFuncAttributeMaxDynamicSharedMemorySize, 131072);
  hipLaunchKernelGGL(gemm256_kernel, dim3(NOUT / 256, MROWS / 256), dim3(512),
                     131072, stream, Ab, Mb, (float*)d_out);
}